// Round 5
// baseline (361.819 us; speedup 1.0000x reference)
//
#include <hip/hip_runtime.h>
#include <hip/hip_bf16.h>
#include <math.h>

// CrossAttention: B=2, S=4096, DIM=256, NH=8, DH=32.
// R4: R2-proven flash shape (32q/wave) + conflict-free pads + key-split x2.
//   K0 prep     : X -> bf16 hi/lo split; W^T via coalesced LDS transpose
//   K1 gemm_qkv : split-bf16 MFMA GEMM -> q(scaled bf16), k(bf16), vT(bf16)
//   K2 flash    : grid 1024 = ks2 x bh16 x qb32; per wave 32 q, 16 k-tiles;
//                 unnormalized fp32 partials + l per split
//   K3 gemm_outp: combine partials, *1/l, split bf16, MFMA GEMM @Wp + bp

#define SCALE 0.17677669529663687f   // 32^-0.5
#define LOG2E 1.4426950408889634f

typedef __attribute__((ext_vector_type(8))) short short8;
typedef __attribute__((ext_vector_type(4))) float f32x4;

static __device__ __forceinline__ unsigned short f2bf(float x) {
    union { float f; unsigned int u; } v; v.f = x;
    unsigned int r = v.u + 0x7fff + ((v.u >> 16) & 1);   // RNE
    return (unsigned short)(r >> 16);
}
static __device__ __forceinline__ float bf2f(unsigned short h) {
    union { unsigned int u; float f; } v; v.u = ((unsigned int)h) << 16;
    return v.f;
}
static __device__ __forceinline__ float fexp2(float x) {
#if __has_builtin(__builtin_amdgcn_exp2f)
    return __builtin_amdgcn_exp2f(x);
#else
    float r; asm("v_exp_f32 %0, %1" : "=v"(r) : "v"(x)); return r;
#endif
}
static __device__ __forceinline__ unsigned int pk_bf16(float a, float b) {
    unsigned int r;
    asm("v_cvt_pk_bf16_f32 %0, %1, %2" : "=v"(r) : "v"(a), "v"(b));
    return r;
}

// -------------------------------------------------- K0: split X + W^T prep
// blocks [0,4096): X split, 4 floats/thread.
// blocks [4096,4160): W 64x64 tile transpose via LDS (coalesced both ways).
__global__ __launch_bounds__(256) void prep(
    const float* __restrict__ query, const float* __restrict__ sim,
    const float* __restrict__ Wq, const float* __restrict__ Wkv,
    const float* __restrict__ Wp,
    unsigned short* __restrict__ xhi, unsigned short* __restrict__ xlo,
    unsigned short* __restrict__ whi, unsigned short* __restrict__ wlo)
{
    __shared__ float T[64][68];
    const int blk = blockIdx.x, t = threadIdx.x;
    if (blk < 4096) {
        const int e = blk * 1024 + t * 4;
        const float* src = (e < 2097152) ? (query + e) : (sim + (e - 2097152));
        float4 v = *(const float4*)src;
        float xv[4] = {v.x, v.y, v.z, v.w};
        union { unsigned short s[4]; uint2 u; } ph, pl;
#pragma unroll
        for (int j = 0; j < 4; ++j) {
            unsigned short h = f2bf(xv[j]);
            ph.s[j] = h;
            pl.s[j] = f2bf(xv[j] - bf2f(h));
        }
        *(uint2*)&xhi[e] = ph.u;
        *(uint2*)&xlo[e] = pl.u;
        return;
    }
    const int bb = blk - 4096;
    const int mat = bb >> 4, tile = bb & 15;
    const int kr0 = (tile >> 2) * 64;      // k rows in source
    const int nc0 = (tile & 3) * 64;       // n cols in source
    const float* src; int ldw, cb; float sc = 1.f;
    if (mat == 0)      { src = Wq;  ldw = 256; cb = 0;   sc = SCALE * LOG2E; }
    else if (mat == 1) { src = Wkv; ldw = 512; cb = 0;   }
    else if (mat == 2) { src = Wkv; ldw = 512; cb = 256; }
    else               { src = Wp;  ldw = 256; cb = 0;   }
    // coalesced load: 64 rows x 64 cols
    {
        const int rl = t >> 4, c4 = (t & 15) * 4;
#pragma unroll
        for (int rr = 0; rr < 4; ++rr) {
            float4 v = *(const float4*)&src[(long long)(kr0 + rr * 16 + rl) * ldw + cb + nc0 + c4];
            T[rr * 16 + rl][c4 + 0] = v.x; T[rr * 16 + rl][c4 + 1] = v.y;
            T[rr * 16 + rl][c4 + 2] = v.z; T[rr * 16 + rl][c4 + 3] = v.w;
        }
    }
    __syncthreads();
    // transposed write: out[n][k] hi/lo, k contiguous
    {
        const int nl = t >> 2, kl0 = (t & 3) * 16;
        const long long orow = (long long)(mat * 256 + nc0 + nl) * 256 + kr0 + kl0;
        union { unsigned short s[16]; uint2 u[4]; } ph, pl;
#pragma unroll
        for (int j = 0; j < 16; ++j) {
            float v = T[kl0 + j][nl] * sc;
            unsigned short h = f2bf(v);
            ph.s[j] = h;
            pl.s[j] = f2bf(v - bf2f(h));
        }
#pragma unroll
        for (int j = 0; j < 4; ++j) {
            *(uint2*)&whi[orow + j * 4] = ph.u[j];
            *(uint2*)&wlo[orow + j * 4] = pl.u[j];
        }
    }
}

// --------------------------------------------------- K1: QKV split-bf16 MFMA
__global__ __launch_bounds__(256) void gemm_qkv(
    const unsigned short* __restrict__ xhi, const unsigned short* __restrict__ xlo,
    const unsigned short* __restrict__ whi, const unsigned short* __restrict__ wlo,
    const float* __restrict__ bq, const float* __restrict__ bkv,
    unsigned short* __restrict__ qbuf, unsigned short* __restrict__ kbuf,
    unsigned short* __restrict__ vTb)
{
    __shared__ unsigned short XsH[64 * 42], XsL[64 * 42];
    __shared__ unsigned short WsH[64 * 42], WsL[64 * 42];

    const int t = threadIdx.x, wave = t >> 6, lane = t & 63;
    const int col = lane & 15, quad = lane >> 4;
    const int by = blockIdx.y;
    const int kind = by >> 2;             // 0=Q 1=K 2=V
    const int n0 = (by & 3) * 64;
    const int m0 = blockIdx.x * 64;
    const int xrow0 = ((kind == 0) ? 0 : 8192) + m0;
    const int wrow0 = kind * 256 + n0;
    const int srow = t >> 2, spart = (t & 3) * 8;

    const f32x4 zero = {0.f, 0.f, 0.f, 0.f};
    f32x4 acc[4] = {zero, zero, zero, zero};

    for (int kt = 0; kt < 8; ++kt) {
        const int k0 = kt * 32;
        uint4 xh = *(const uint4*)&xhi[(long long)(xrow0 + srow) * 256 + k0 + spart];
        uint4 xl = *(const uint4*)&xlo[(long long)(xrow0 + srow) * 256 + k0 + spart];
        uint4 wh = *(const uint4*)&whi[(long long)(wrow0 + srow) * 256 + k0 + spart];
        uint4 wl = *(const uint4*)&wlo[(long long)(wrow0 + srow) * 256 + k0 + spart];
        __syncthreads();
        *(uint4*)&XsH[srow * 42 + spart] = xh;
        *(uint4*)&XsL[srow * 42 + spart] = xl;
        *(uint4*)&WsH[srow * 42 + spart] = wh;
        *(uint4*)&WsL[srow * 42 + spart] = wl;
        __syncthreads();

        const unsigned short* Ah = (kind == 2) ? WsH : XsH;
        const unsigned short* Al = (kind == 2) ? WsL : XsL;
        const unsigned short* Bh = (kind == 2) ? XsH : WsH;
        const unsigned short* Bl = (kind == 2) ? XsL : WsL;

        short8 a_h = *(const short8*)(Ah + (wave * 16 + col) * 42 + quad * 8);
        short8 a_l = *(const short8*)(Al + (wave * 16 + col) * 42 + quad * 8);
#pragma unroll
        for (int nt = 0; nt < 4; ++nt) {
            short8 b_h = *(const short8*)(Bh + (nt * 16 + col) * 42 + quad * 8);
            short8 b_l = *(const short8*)(Bl + (nt * 16 + col) * 42 + quad * 8);
            acc[nt] = __builtin_amdgcn_mfma_f32_16x16x32_bf16(a_h, b_h, acc[nt], 0, 0, 0);
            acc[nt] = __builtin_amdgcn_mfma_f32_16x16x32_bf16(a_l, b_h, acc[nt], 0, 0, 0);
            acc[nt] = __builtin_amdgcn_mfma_f32_16x16x32_bf16(a_h, b_l, acc[nt], 0, 0, 0);
        }
    }

    if (kind == 0) {
#pragma unroll
        for (int nt = 0; nt < 4; ++nt) {
            int n = n0 + nt * 16 + col;
            int h = n >> 5, d = n & 31;
            float bias = bq[n] * (SCALE * LOG2E);
#pragma unroll
            for (int r = 0; r < 4; ++r) {
                int mg = m0 + wave * 16 + quad * 4 + r;
                int b = mg >> 12, sidx = mg & 4095;
                qbuf[((long long)(b * 8 + h) * 4096 + sidx) * 32 + d] = f2bf(acc[nt][r] + bias);
            }
        }
    } else if (kind == 1) {
#pragma unroll
        for (int nt = 0; nt < 4; ++nt) {
            int n = n0 + nt * 16 + col;
            int h = n >> 5, d = n & 31;
            float bias = bkv[n];
#pragma unroll
            for (int r = 0; r < 4; ++r) {
                int mg = m0 + wave * 16 + quad * 4 + r;
                int b = mg >> 12, sidx = mg & 4095;
                kbuf[((long long)(b * 8 + h) * 4096 + sidx) * 32 + d] = f2bf(acc[nt][r] + bias);
            }
        }
    } else {   // V transposed: C[m'=feature][n'=s]
#pragma unroll
        for (int nt = 0; nt < 4; ++nt) {
            int s = m0 + nt * 16 + col;
            int b = s >> 12, sidx = s & 4095;
#pragma unroll
            for (int r = 0; r < 4; ++r) {
                int dcol = n0 + wave * 16 + quad * 4 + r;
                int h = dcol >> 5, dd = dcol & 31;
                float bias = bkv[256 + dcol];
                vTb[((long long)((b * 8 + h) * 32 + dd)) * 4096 + sidx] = f2bf(acc[nt][r] + bias);
            }
        }
    }
}

// ------------------------------------------------------------ K2: flash MFMA
// grid 1024 = ks(2) x bh(16) x qb(32); block 256 (4 waves x 32 q).
__global__ __launch_bounds__(256) void flash_mfma(
    const unsigned short* __restrict__ qbuf,
    const unsigned short* __restrict__ kbuf,
    const unsigned short* __restrict__ vT,
    float* __restrict__ xpart, float* __restrict__ lpart)
{
    __shared__ unsigned short Ks[128 * 42];      // [key][dh] stride 42
    __shared__ unsigned short Vt[32 * 138];      // [dh][key] stride 138
    __shared__ unsigned short Pb[8][16 * 42];    // [wave*2+tile][q][key]

    const int t = threadIdx.x;
    const int wave = t >> 6, lane = t & 63;
    const int col = lane & 15, quad = lane >> 4;
    const int qb = blockIdx.x & 31;
    const int bh = (blockIdx.x >> 5) & 15;
    const int ks = blockIdx.x >> 9;
    const int q0 = qb * 128 + wave * 32;
    const long long kvbase = (long long)bh * 4096 * 32;
    unsigned short* pb0 = Pb[wave * 2];
    unsigned short* pb1 = Pb[wave * 2 + 1];

    const short8 qf0 = *(const short8*)(qbuf + kvbase + (long long)(q0 + col) * 32 + quad * 8);
    const short8 qf1 = *(const short8*)(qbuf + kvbase + (long long)(q0 + 16 + col) * 32 + quad * 8);

    const f32x4 zero = {0.f, 0.f, 0.f, 0.f};
    f32x4 o00 = zero, o01 = zero, o10 = zero, o11 = zero;
    float l0 = 0.f, l1 = 0.f;

    const int krow = t >> 2, kpart = (t & 3) * 8;
    const int vrow = t >> 4, vpart = (t & 15) * 8;

    for (int kt0 = 0; kt0 < 16; ++kt0) {
        const int kt = ks * 16 + kt0;
        uint4 kg0 = *(const uint4*)(kbuf + kvbase + (long long)(kt * 128 + krow) * 32 + kpart);
        uint4 kg1 = *(const uint4*)(kbuf + kvbase + (long long)(kt * 128 + krow + 64) * 32 + kpart);
        uint4 vg0 = *(const uint4*)(vT + ((long long)(bh * 32 + vrow)) * 4096 + kt * 128 + vpart);
        uint4 vg1 = *(const uint4*)(vT + ((long long)(bh * 32 + vrow + 16)) * 4096 + kt * 128 + vpart);
        __syncthreads();
        *(uint4*)(Ks + krow * 42 + kpart) = kg0;
        *(uint4*)(Ks + (krow + 64) * 42 + kpart) = kg1;
        *(uint4*)(Vt + vrow * 138 + vpart) = vg0;
        *(uint4*)(Vt + (vrow + 16) * 138 + vpart) = vg1;
        __syncthreads();

#pragma unroll
        for (int sb = 0; sb < 4; ++sb) {
            const int kb = sb * 32;
            short8 a0 = *(const short8*)(Ks + (kb + col) * 42 + quad * 8);
            short8 a1 = *(const short8*)(Ks + (kb + 16 + col) * 42 + quad * 8);
            short8 v0 = *(const short8*)(Vt + col * 138 + kb + quad * 8);
            short8 v1 = *(const short8*)(Vt + (16 + col) * 138 + kb + quad * 8);
            // ---- q-tile 0
            {
                f32x4 c0 = __builtin_amdgcn_mfma_f32_16x16x32_bf16(a0, qf0, zero, 0, 0, 0);
                f32x4 c1 = __builtin_amdgcn_mfma_f32_16x16x32_bf16(a1, qf0, zero, 0, 0, 0);
                float p0 = fexp2(c0[0]), p1 = fexp2(c0[1]), p2 = fexp2(c0[2]), p3 = fexp2(c0[3]);
                float p4 = fexp2(c1[0]), p5 = fexp2(c1[1]), p6 = fexp2(c1[2]), p7 = fexp2(c1[3]);
                l0 += ((p0 + p1) + (p2 + p3)) + ((p4 + p5) + (p6 + p7));
                uint2 w0 = make_uint2(pk_bf16(p0, p1), pk_bf16(p2, p3));
                uint2 w1 = make_uint2(pk_bf16(p4, p5), pk_bf16(p6, p7));
                *(uint2*)(pb0 + col * 42 + quad * 4) = w0;
                *(uint2*)(pb0 + col * 42 + 16 + quad * 4) = w1;
                short8 pf = *(const short8*)(pb0 + col * 42 + quad * 8);
                o00 = __builtin_amdgcn_mfma_f32_16x16x32_bf16(v0, pf, o00, 0, 0, 0);
                o01 = __builtin_amdgcn_mfma_f32_16x16x32_bf16(v1, pf, o01, 0, 0, 0);
            }
            // ---- q-tile 1
            {
                f32x4 c0 = __builtin_amdgcn_mfma_f32_16x16x32_bf16(a0, qf1, zero, 0, 0, 0);
                f32x4 c1 = __builtin_amdgcn_mfma_f32_16x16x32_bf16(a1, qf1, zero, 0, 0, 0);
                float p0 = fexp2(c0[0]), p1 = fexp2(c0[1]), p2 = fexp2(c0[2]), p3 = fexp2(c0[3]);
                float p4 = fexp2(c1[0]), p5 = fexp2(c1[1]), p6 = fexp2(c1[2]), p7 = fexp2(c1[3]);
                l1 += ((p0 + p1) + (p2 + p3)) + ((p4 + p5) + (p6 + p7));
                uint2 w0 = make_uint2(pk_bf16(p0, p1), pk_bf16(p2, p3));
                uint2 w1 = make_uint2(pk_bf16(p4, p5), pk_bf16(p6, p7));
                *(uint2*)(pb1 + col * 42 + quad * 4) = w0;
                *(uint2*)(pb1 + col * 42 + 16 + quad * 4) = w1;
                short8 pf = *(const short8*)(pb1 + col * 42 + quad * 8);
                o10 = __builtin_amdgcn_mfma_f32_16x16x32_bf16(v0, pf, o10, 0, 0, 0);
                o11 = __builtin_amdgcn_mfma_f32_16x16x32_bf16(v1, pf, o11, 0, 0, 0);
            }
        }
    }

    l0 += __shfl_xor(l0, 16, 64); l0 += __shfl_xor(l0, 32, 64);
    l1 += __shfl_xor(l1, 16, 64); l1 += __shfl_xor(l1, 32, 64);

    const int b = bh >> 3, hh = bh & 7;
    float* xp = xpart + (long long)ks * 2097152;
    float* r0p = xp + ((long long)(b * 4096 + q0 + col)) * 256 + hh * 32;
    *(float4*)(r0p + quad * 4)      = make_float4(o00[0], o00[1], o00[2], o00[3]);
    *(float4*)(r0p + 16 + quad * 4) = make_float4(o01[0], o01[1], o01[2], o01[3]);
    float* r1p = xp + ((long long)(b * 4096 + q0 + 16 + col)) * 256 + hh * 32;
    *(float4*)(r1p + quad * 4)      = make_float4(o10[0], o10[1], o10[2], o10[3]);
    *(float4*)(r1p + 16 + quad * 4) = make_float4(o11[0], o11[1], o11[2], o11[3]);

    if (quad == 0)      lpart[ks * 65536 + bh * 4096 + q0 + col] = l0;
    else if (quad == 1) lpart[ks * 65536 + bh * 4096 + q0 + 16 + col] = l1;
}

// ----------------------------------- K3: combine + normalize + out-proj MFMA
__global__ __launch_bounds__(256) void gemm_outp(
    const float* __restrict__ xpart, const float* __restrict__ lpart,
    const unsigned short* __restrict__ whi, const unsigned short* __restrict__ wlo,
    const float* __restrict__ bp, float* __restrict__ out)
{
    __shared__ unsigned short XsH[64 * 42], XsL[64 * 42];
    __shared__ unsigned short WsH[64 * 42], WsL[64 * 42];

    const int t = threadIdx.x, wave = t >> 6, lane = t & 63;
    const int col = lane & 15, quad = lane >> 4;
    const int n0 = blockIdx.y * 64;
    const int m0 = blockIdx.x * 64;
    const int srow = t >> 2, spart = (t & 3) * 8;
    const int r = m0 + srow;
    const int bidx = r >> 12, s = r & 4095;
    const float* __restrict__ xa = xpart;
    const float* __restrict__ xb = xpart + 2097152;

    const f32x4 zero = {0.f, 0.f, 0.f, 0.f};
    f32x4 acc[4] = {zero, zero, zero, zero};

    for (int kt = 0; kt < 8; ++kt) {
        const int k0 = kt * 32;
        const int head = k0 >> 5;
        float la = lpart[(bidx * 8 + head) * 4096 + s];
        float lb = lpart[65536 + (bidx * 8 + head) * 4096 + s];
        float linv = 1.f / (la + lb);
        const float* pa = &xa[(long long)r * 256 + k0 + spart];
        const float* pb = &xb[(long long)r * 256 + k0 + spart];
        float4 a0 = *(const float4*)pa, a1 = *(const float4*)(pa + 4);
        float4 b0 = *(const float4*)pb, b1 = *(const float4*)(pb + 4);
        float xc[8] = {(a0.x + b0.x) * linv, (a0.y + b0.y) * linv,
                       (a0.z + b0.z) * linv, (a0.w + b0.w) * linv,
                       (a1.x + b1.x) * linv, (a1.y + b1.y) * linv,
                       (a1.z + b1.z) * linv, (a1.w + b1.w) * linv};
        union { unsigned short s4[8]; uint4 u; } ph, pl;
#pragma unroll
        for (int j = 0; j < 8; ++j) {
            unsigned short h = f2bf(xc[j]);
            ph.s4[j] = h;
            pl.s4[j] = f2bf(xc[j] - bf2f(h));
        }
        uint4 wh = *(const uint4*)&whi[(long long)(768 + n0 + srow) * 256 + k0 + spart];
        uint4 wl = *(const uint4*)&wlo[(long long)(768 + n0 + srow) * 256 + k0 + spart];
        __syncthreads();
        *(uint4*)&XsH[srow * 42 + spart] = ph.u;
        *(uint4*)&XsL[srow * 42 + spart] = pl.u;
        *(uint4*)&WsH[srow * 42 + spart] = wh;
        *(uint4*)&WsL[srow * 42 + spart] = wl;
        __syncthreads();

        short8 a_h = *(const short8*)(XsH + (wave * 16 + col) * 42 + quad * 8);
        short8 a_l = *(const short8*)(XsL + (wave * 16 + col) * 42 + quad * 8);
#pragma unroll
        for (int nt = 0; nt < 4; ++nt) {
            short8 b_h = *(const short8*)(WsH + (nt * 16 + col) * 42 + quad * 8);
            short8 b_l = *(const short8*)(WsL + (nt * 16 + col) * 42 + quad * 8);
            acc[nt] = __builtin_amdgcn_mfma_f32_16x16x32_bf16(a_h, b_h, acc[nt], 0, 0, 0);
            acc[nt] = __builtin_amdgcn_mfma_f32_16x16x32_bf16(a_l, b_h, acc[nt], 0, 0, 0);
            acc[nt] = __builtin_amdgcn_mfma_f32_16x16x32_bf16(a_h, b_l, acc[nt], 0, 0, 0);
        }
    }

#pragma unroll
    for (int nt = 0; nt < 4; ++nt) {
        int n = n0 + nt * 16 + col;
        float bias = bp[n];
#pragma unroll
        for (int rr = 0; rr < 4; ++rr) {
            int mg = m0 + wave * 16 + quad * 4 + rr;
            out[(long long)mg * 256 + n] = acc[nt][rr] + bias;
        }
    }
}

extern "C" void kernel_launch(void* const* d_in, const int* in_sizes, int n_in,
                              void* d_out, int out_size, void* d_ws, size_t ws_size,
                              hipStream_t stream) {
    const float* query = (const float*)d_in[0];
    const float* sim   = (const float*)d_in[1];
    const float* Wq    = (const float*)d_in[2];
    const float* bq    = (const float*)d_in[3];
    const float* Wkv   = (const float*)d_in[4];
    const float* bkv   = (const float*)d_in[5];
    const float* Wp    = (const float*)d_in[6];
    const float* bp    = (const float*)d_in[7];
    float* out = (float*)d_out;

    unsigned short* wsb = (unsigned short*)d_ws;
    unsigned short* qbuf = wsb;                       // 2,097,152 shorts
    unsigned short* kbuf = wsb + 2097152;
    unsigned short* vT   = wsb + 4194304;             // ends 6,291,456
    unsigned short* whi  = wsb + 6291456;             // 262,144
    unsigned short* wlo  = wsb + 6553600;             // ends 6,815,744
    // xhi/xlo live only until gemm_qkv completes; xpart/lpart alias them after.
    unsigned short* xhi  = wsb + 6815744;             // 4,194,304
    unsigned short* xlo  = wsb + 11010048;            // ends 15,204,352
    float* xpart = (float*)(wsb + 6815744);           // 2 x 2,097,152 floats
    float* lpart = xpart + 4194304;                   // 2 x 65,536 floats

    prep      <<<dim3(4160),    256, 0, stream>>>(query, sim, Wq, Wkv, Wp,
                                                  xhi, xlo, whi, wlo);
    gemm_qkv  <<<dim3(128, 12), 256, 0, stream>>>(xhi, xlo, whi, wlo, bq, bkv,
                                                  qbuf, kbuf, vT);
    flash_mfma<<<dim3(1024),    256, 0, stream>>>(qbuf, kbuf, vT, xpart, lpart);
    gemm_outp <<<dim3(128, 4),  256, 0, stream>>>(xpart, lpart, whi, wlo, bp, out);
}

// Round 6
// 199.934 us; speedup vs baseline: 1.8097x; 1.8097x over previous
//
#include <hip/hip_runtime.h>
#include <hip/hip_bf16.h>
#include <math.h>

// CrossAttention: B=2, S=4096, DIM=256, NH=8, DH=32.
// R5 = verbatim R2 pipeline (176us: flash 77 + rest 99) with ONE change:
// flash reads K/V fragments directly from global (L2-resident, 512KB/head),
// deleting LDS staging + both per-iteration barriers. P-roundtrip unchanged.
//   K0 prep_w   : transpose+bf16-split W matrices -> [n][k] hi/lo (Wq prescaled)
//   K1 gemm_qkv : split-bf16 MFMA GEMM -> q(bf16, scaled), k(bf16), vT(bf16)
//   K2 flash    : 32 q/wave, direct-global K/V frags, exp2, P via LDS roundtrip
//   K3 gemm_out : split-bf16 MFMA GEMM xbuf @ Wp + bp -> fp32 out

#define SCALE 0.17677669529663687f   // 32^-0.5
#define LOG2E 1.4426950408889634f

typedef __attribute__((ext_vector_type(8))) short short8;
typedef __attribute__((ext_vector_type(4))) float f32x4;

static __device__ __forceinline__ unsigned short f2bf(float x) {
    union { float f; unsigned int u; } v; v.f = x;
    unsigned int r = v.u + 0x7fff + ((v.u >> 16) & 1);   // RNE
    return (unsigned short)(r >> 16);
}
static __device__ __forceinline__ float bf2f(unsigned short h) {
    union { unsigned int u; float f; } v; v.u = ((unsigned int)h) << 16;
    return v.f;
}
static __device__ __forceinline__ float fexp2(float x) {
#if __has_builtin(__builtin_amdgcn_exp2f)
    return __builtin_amdgcn_exp2f(x);
#else
    float r; asm("v_exp_f32 %0, %1" : "=v"(r) : "v"(x)); return r;
#endif
}
// packed bf16 convert: low half = a, high half = b (gfx950 V_CVT_PK_BF16_F32)
static __device__ __forceinline__ unsigned int pk_bf16(float a, float b) {
    unsigned int r;
    asm("v_cvt_pk_bf16_f32 %0, %1, %2" : "=v"(r) : "v"(a), "v"(b));
    return r;
}

// ------------------------------------------------------- K0: W transpose+split
// grid 1024 x 256. Row layout: [0,256)=WqT(scaled) [256,512)=WkT [512,768)=WvT
// [768,1024)=WpT.  Output [n][k] bf16 hi/lo, k contiguous (256).
__global__ __launch_bounds__(256) void prep_w(
    const float* __restrict__ Wq, const float* __restrict__ Wkv,
    const float* __restrict__ Wp,
    unsigned short* __restrict__ whi, unsigned short* __restrict__ wlo)
{
    const int n = blockIdx.x & 255, mat = blockIdx.x >> 8, k = threadIdx.x;
    const float* src; int ldw, colx; float sc = 1.f;
    if (mat == 0)      { src = Wq;  ldw = 256; colx = n;       sc = SCALE * LOG2E; }
    else if (mat == 1) { src = Wkv; ldw = 512; colx = n;       }
    else if (mat == 2) { src = Wkv; ldw = 512; colx = n + 256; }
    else               { src = Wp;  ldw = 256; colx = n;       }
    float v = src[(long long)k * ldw + colx] * sc;
    unsigned short h = f2bf(v);
    unsigned short l = f2bf(v - bf2f(h));
    const int o = blockIdx.x * 256 + k;
    whi[o] = h; wlo[o] = l;
}

// --------------------------------------------------- K1: QKV split-bf16 MFMA
__global__ __launch_bounds__(256) void gemm_qkv(
    const float* __restrict__ query, const float* __restrict__ sim,
    const unsigned short* __restrict__ whi, const unsigned short* __restrict__ wlo,
    const float* __restrict__ bq, const float* __restrict__ bkv,
    unsigned short* __restrict__ qbuf, unsigned short* __restrict__ kbuf,
    unsigned short* __restrict__ vTb)
{
    __shared__ unsigned short XsH[64 * 40], XsL[64 * 40];
    __shared__ unsigned short WsH[64 * 40], WsL[64 * 40];

    const int t = threadIdx.x, wave = t >> 6, lane = t & 63;
    const int col = lane & 15, quad = lane >> 4;
    const int by = blockIdx.y;
    const int kind = by >> 2;             // 0=Q 1=K 2=V
    const int n0 = (by & 3) * 64;
    const int m0 = blockIdx.x * 64;
    const float* __restrict__ X = (kind == 0) ? query : sim;
    const int wrow0 = kind * 256 + n0;
    const int srow = t >> 2, spart = (t & 3) * 8;

    const f32x4 zero = {0.f, 0.f, 0.f, 0.f};
    f32x4 acc[4] = {zero, zero, zero, zero};

    for (int kt = 0; kt < 8; ++kt) {
        const int k0 = kt * 32;
        const float* xp = &X[(long long)(m0 + srow) * 256 + k0 + spart];
        float4 xa = *(const float4*)xp;
        float4 xb = *(const float4*)(xp + 4);
        float xv[8] = {xa.x, xa.y, xa.z, xa.w, xb.x, xb.y, xb.z, xb.w};
        union { unsigned short s[8]; uint4 u; } ph, pl;
#pragma unroll
        for (int j = 0; j < 8; ++j) {
            unsigned short h = f2bf(xv[j]);
            ph.s[j] = h;
            pl.s[j] = f2bf(xv[j] - bf2f(h));
        }
        uint4 wh = *(const uint4*)&whi[(long long)(wrow0 + srow) * 256 + k0 + spart];
        uint4 wl = *(const uint4*)&wlo[(long long)(wrow0 + srow) * 256 + k0 + spart];
        __syncthreads();
        *(uint4*)&XsH[srow * 40 + spart] = ph.u;
        *(uint4*)&XsL[srow * 40 + spart] = pl.u;
        *(uint4*)&WsH[srow * 40 + spart] = wh;
        *(uint4*)&WsL[srow * 40 + spart] = wl;
        __syncthreads();

        const unsigned short* Ah = (kind == 2) ? WsH : XsH;
        const unsigned short* Al = (kind == 2) ? WsL : XsL;
        const unsigned short* Bh = (kind == 2) ? XsH : WsH;
        const unsigned short* Bl = (kind == 2) ? XsL : WsL;

        short8 a_h = *(const short8*)(Ah + (wave * 16 + col) * 40 + quad * 8);
        short8 a_l = *(const short8*)(Al + (wave * 16 + col) * 40 + quad * 8);
#pragma unroll
        for (int nt = 0; nt < 4; ++nt) {
            short8 b_h = *(const short8*)(Bh + (nt * 16 + col) * 40 + quad * 8);
            short8 b_l = *(const short8*)(Bl + (nt * 16 + col) * 40 + quad * 8);
            acc[nt] = __builtin_amdgcn_mfma_f32_16x16x32_bf16(a_h, b_h, acc[nt], 0, 0, 0);
            acc[nt] = __builtin_amdgcn_mfma_f32_16x16x32_bf16(a_l, b_h, acc[nt], 0, 0, 0);
            acc[nt] = __builtin_amdgcn_mfma_f32_16x16x32_bf16(a_h, b_l, acc[nt], 0, 0, 0);
        }
    }

    if (kind == 0) {
#pragma unroll
        for (int nt = 0; nt < 4; ++nt) {
            int n = n0 + nt * 16 + col;
            int h = n >> 5, d = n & 31;
            float bias = bq[n] * (SCALE * LOG2E);
#pragma unroll
            for (int r = 0; r < 4; ++r) {
                int mg = m0 + wave * 16 + quad * 4 + r;
                int b = mg >> 12, sidx = mg & 4095;
                qbuf[((long long)(b * 8 + h) * 4096 + sidx) * 32 + d] = f2bf(acc[nt][r] + bias);
            }
        }
    } else if (kind == 1) {
#pragma unroll
        for (int nt = 0; nt < 4; ++nt) {
            int n = n0 + nt * 16 + col;
            int h = n >> 5, d = n & 31;
            float bias = bkv[n];
#pragma unroll
            for (int r = 0; r < 4; ++r) {
                int mg = m0 + wave * 16 + quad * 4 + r;
                int b = mg >> 12, sidx = mg & 4095;
                kbuf[((long long)(b * 8 + h) * 4096 + sidx) * 32 + d] = f2bf(acc[nt][r] + bias);
            }
        }
    } else {   // V, computed transposed: C[m'=feature][n'=s]
#pragma unroll
        for (int nt = 0; nt < 4; ++nt) {
            int s = m0 + nt * 16 + col;
            int b = s >> 12, sidx = s & 4095;
#pragma unroll
            for (int r = 0; r < 4; ++r) {
                int dcol = n0 + wave * 16 + quad * 4 + r;
                int h = dcol >> 5, dd = dcol & 31;
                float bias = bkv[256 + dcol];
                vTb[((long long)((b * 8 + h) * 32 + dd)) * 4096 + sidx] = f2bf(acc[nt][r] + bias);
            }
        }
    }
}

// ------------------------------------------------------------ K2: flash MFMA
// grid 512 (16 bh x 32 q-blocks of 128), block 256. Wave owns 32 q (2 tiles).
// K/V fragments read DIRECTLY from global (L2-resident); no LDS staging, no
// per-iteration barriers. P relayout via per-wave LDS roundtrip (same-wave).
__global__ __launch_bounds__(256) void flash_mfma(
    const unsigned short* __restrict__ qbuf,
    const unsigned short* __restrict__ kbuf,
    const unsigned short* __restrict__ vT,
    float* __restrict__ xbuf)
{
    __shared__ unsigned short Pb[4][640];        // per-wave [q16][key] pad 32->40

    const int t = threadIdx.x;
    const int wave = t >> 6, lane = t & 63;
    const int col = lane & 15, quad = lane >> 4;
    const int bh = blockIdx.x >> 5;
    const int q0 = (blockIdx.x & 31) * 128 + wave * 32;
    const long long kvbase = (long long)bh * 4096 * 32;
    unsigned short* pbw = Pb[wave];

    const short8 qf0 = *(const short8*)(qbuf + kvbase + (long long)(q0 + col) * 32 + quad * 8);
    const short8 qf1 = *(const short8*)(qbuf + kvbase + (long long)(q0 + 16 + col) * 32 + quad * 8);

    const f32x4 zero = {0.f, 0.f, 0.f, 0.f};
    f32x4 o00 = zero, o01 = zero, o10 = zero, o11 = zero;
    float l0 = 0.f, l1 = 0.f;

    // per-lane base pointers for direct K/V fragment loads
    const unsigned short* kp = kbuf + kvbase + (long long)col * 32 + quad * 8;
    const unsigned short* vp = vT + ((long long)(bh * 32 + col)) * 4096 + quad * 8;

    for (int kt = 0; kt < 32; ++kt) {
        const unsigned short* kpt = kp + kt * 128 * 32;
        const unsigned short* vpt = vp + kt * 128;

#pragma unroll
        for (int sb = 0; sb < 4; ++sb) {
            const int kb = sb * 32;
            // A = K tile: A[m=key=col][k=dh=quad*8+j]  (rows kb+col, kb+16+col)
            short8 a0 = *(const short8*)(kpt + (long long)kb * 32);
            short8 a1 = *(const short8*)(kpt + (long long)(kb + 16) * 32);
            // A = Vt tile: A[m=dh=h*16+col][k=key=kb+quad*8+j]
            short8 v0 = *(const short8*)(vpt + kb);
            short8 v1 = *(const short8*)(vpt + (long long)16 * 4096 + kb);
            // ---- q-tile 0
            {
                f32x4 c0 = __builtin_amdgcn_mfma_f32_16x16x32_bf16(a0, qf0, zero, 0, 0, 0);
                f32x4 c1 = __builtin_amdgcn_mfma_f32_16x16x32_bf16(a1, qf0, zero, 0, 0, 0);
                float p0 = fexp2(c0[0]), p1 = fexp2(c0[1]), p2 = fexp2(c0[2]), p3 = fexp2(c0[3]);
                float p4 = fexp2(c1[0]), p5 = fexp2(c1[1]), p6 = fexp2(c1[2]), p7 = fexp2(c1[3]);
                l0 += ((p0 + p1) + (p2 + p3)) + ((p4 + p5) + (p6 + p7));
                uint2 w0 = make_uint2(pk_bf16(p0, p1), pk_bf16(p2, p3));
                uint2 w1 = make_uint2(pk_bf16(p4, p5), pk_bf16(p6, p7));
                *(uint2*)(pbw + col * 40 + quad * 4) = w0;
                *(uint2*)(pbw + col * 40 + 16 + quad * 4) = w1;
                short8 pf = *(const short8*)(pbw + col * 40 + quad * 8);
                o00 = __builtin_amdgcn_mfma_f32_16x16x32_bf16(v0, pf, o00, 0, 0, 0);
                o01 = __builtin_amdgcn_mfma_f32_16x16x32_bf16(v1, pf, o01, 0, 0, 0);
            }
            // ---- q-tile 1 (reuse a0,a1,v0,v1)
            {
                f32x4 c0 = __builtin_amdgcn_mfma_f32_16x16x32_bf16(a0, qf1, zero, 0, 0, 0);
                f32x4 c1 = __builtin_amdgcn_mfma_f32_16x16x32_bf16(a1, qf1, zero, 0, 0, 0);
                float p0 = fexp2(c0[0]), p1 = fexp2(c0[1]), p2 = fexp2(c0[2]), p3 = fexp2(c0[3]);
                float p4 = fexp2(c1[0]), p5 = fexp2(c1[1]), p6 = fexp2(c1[2]), p7 = fexp2(c1[3]);
                l1 += ((p0 + p1) + (p2 + p3)) + ((p4 + p5) + (p6 + p7));
                uint2 w0 = make_uint2(pk_bf16(p0, p1), pk_bf16(p2, p3));
                uint2 w1 = make_uint2(pk_bf16(p4, p5), pk_bf16(p6, p7));
                *(uint2*)(pbw + col * 40 + quad * 4) = w0;
                *(uint2*)(pbw + col * 40 + 16 + quad * 4) = w1;
                short8 pf = *(const short8*)(pbw + col * 40 + quad * 8);
                o10 = __builtin_amdgcn_mfma_f32_16x16x32_bf16(v0, pf, o10, 0, 0, 0);
                o11 = __builtin_amdgcn_mfma_f32_16x16x32_bf16(v1, pf, o11, 0, 0, 0);
            }
        }
    }

    l0 += __shfl_xor(l0, 16, 64); l0 += __shfl_xor(l0, 32, 64);
    l1 += __shfl_xor(l1, 16, 64); l1 += __shfl_xor(l1, 32, 64);
    const float i0 = 1.f / l0, i1 = 1.f / l1;

    const int b = bh >> 3, hh = bh & 7;
    float* xp0 = xbuf + ((long long)(b * 4096 + q0 + col)) * 256 + hh * 32;
    *(float4*)(xp0 + quad * 4)      = make_float4(o00[0] * i0, o00[1] * i0, o00[2] * i0, o00[3] * i0);
    *(float4*)(xp0 + 16 + quad * 4) = make_float4(o01[0] * i0, o01[1] * i0, o01[2] * i0, o01[3] * i0);
    float* xp1 = xbuf + ((long long)(b * 4096 + q0 + 16 + col)) * 256 + hh * 32;
    *(float4*)(xp1 + quad * 4)      = make_float4(o10[0] * i1, o10[1] * i1, o10[2] * i1, o10[3] * i1);
    *(float4*)(xp1 + 16 + quad * 4) = make_float4(o11[0] * i1, o11[1] * i1, o11[2] * i1, o11[3] * i1);
}

// --------------------------------------------------- K3: out split-bf16 MFMA
__global__ __launch_bounds__(256) void gemm_outp(
    const float* __restrict__ xbuf,
    const unsigned short* __restrict__ whi, const unsigned short* __restrict__ wlo,
    const float* __restrict__ bp, float* __restrict__ out)
{
    __shared__ unsigned short XsH[64 * 40], XsL[64 * 40];
    __shared__ unsigned short WsH[64 * 40], WsL[64 * 40];

    const int t = threadIdx.x, wave = t >> 6, lane = t & 63;
    const int col = lane & 15, quad = lane >> 4;
    const int n0 = blockIdx.y * 64;
    const int m0 = blockIdx.x * 64;
    const int wrow0 = 768 + n0;
    const int srow = t >> 2, spart = (t & 3) * 8;

    const f32x4 zero = {0.f, 0.f, 0.f, 0.f};
    f32x4 acc[4] = {zero, zero, zero, zero};

    for (int kt = 0; kt < 8; ++kt) {
        const int k0 = kt * 32;
        const float* xp = &xbuf[(long long)(m0 + srow) * 256 + k0 + spart];
        float4 xa = *(const float4*)xp;
        float4 xb = *(const float4*)(xp + 4);
        float xv[8] = {xa.x, xa.y, xa.z, xa.w, xb.x, xb.y, xb.z, xb.w};
        union { unsigned short s[8]; uint4 u; } ph, pl;
#pragma unroll
        for (int j = 0; j < 8; ++j) {
            unsigned short h = f2bf(xv[j]);
            ph.s[j] = h;
            pl.s[j] = f2bf(xv[j] - bf2f(h));
        }
        uint4 wh = *(const uint4*)&whi[(long long)(wrow0 + srow) * 256 + k0 + spart];
        uint4 wl = *(const uint4*)&wlo[(long long)(wrow0 + srow) * 256 + k0 + spart];
        __syncthreads();
        *(uint4*)&XsH[srow * 40 + spart] = ph.u;
        *(uint4*)&XsL[srow * 40 + spart] = pl.u;
        *(uint4*)&WsH[srow * 40 + spart] = wh;
        *(uint4*)&WsL[srow * 40 + spart] = wl;
        __syncthreads();

        short8 a_h = *(const short8*)(XsH + (wave * 16 + col) * 40 + quad * 8);
        short8 a_l = *(const short8*)(XsL + (wave * 16 + col) * 40 + quad * 8);
#pragma unroll
        for (int nt = 0; nt < 4; ++nt) {
            short8 b_h = *(const short8*)(WsH + (nt * 16 + col) * 40 + quad * 8);
            short8 b_l = *(const short8*)(WsL + (nt * 16 + col) * 40 + quad * 8);
            acc[nt] = __builtin_amdgcn_mfma_f32_16x16x32_bf16(a_h, b_h, acc[nt], 0, 0, 0);
            acc[nt] = __builtin_amdgcn_mfma_f32_16x16x32_bf16(a_l, b_h, acc[nt], 0, 0, 0);
            acc[nt] = __builtin_amdgcn_mfma_f32_16x16x32_bf16(a_h, b_l, acc[nt], 0, 0, 0);
        }
    }

#pragma unroll
    for (int nt = 0; nt < 4; ++nt) {
        int n = n0 + nt * 16 + col;
        float bias = bp[n];
#pragma unroll
        for (int r = 0; r < 4; ++r) {
            int mg = m0 + wave * 16 + quad * 4 + r;
            out[(long long)mg * 256 + n] = acc[nt][r] + bias;
        }
    }
}

extern "C" void kernel_launch(void* const* d_in, const int* in_sizes, int n_in,
                              void* d_out, int out_size, void* d_ws, size_t ws_size,
                              hipStream_t stream) {
    const float* query = (const float*)d_in[0];
    const float* sim   = (const float*)d_in[1];
    const float* Wq    = (const float*)d_in[2];
    const float* bq    = (const float*)d_in[3];
    const float* Wkv   = (const float*)d_in[4];
    const float* bkv   = (const float*)d_in[5];
    const float* Wp    = (const float*)d_in[6];
    const float* bp    = (const float*)d_in[7];
    float* out = (float*)d_out;

    unsigned short* wsb = (unsigned short*)d_ws;
    unsigned short* qbuf = wsb;                        // 2,097,152 shorts
    unsigned short* kbuf = wsb + 2097152;
    unsigned short* vT   = wsb + 4194304;              // [bh][32][4096]
    float* xbuf = (float*)(wsb + 6291456);             // 2,097,152 floats
    unsigned short* whi  = wsb + 10485760;             // 1024*256
    unsigned short* wlo  = whi + 262144;

    prep_w   <<<dim3(1024),    256, 0, stream>>>(Wq, Wkv, Wp, whi, wlo);
    gemm_qkv <<<dim3(128, 12), 256, 0, stream>>>(query, sim, whi, wlo, bq, bkv,
                                                 qbuf, kbuf, vT);
    flash_mfma<<<dim3(512),    256, 0, stream>>>(qbuf, kbuf, vT, xbuf);
    gemm_outp<<<dim3(128, 4),  256, 0, stream>>>(xbuf, whi, wlo, bp, out);
}